// Round 7
// baseline (93.043 us; speedup 1.0000x reference)
//
#include <hip/hip_runtime.h>

#define B_ 4
#define QN 512
#define KVN 512
#define QD_ 512
#define H_ 256
#define VD_ 256
#define TOTR 2048  // B_*QN

typedef __attribute__((ext_vector_type(8))) short bf16x8;
typedef __attribute__((ext_vector_type(4))) float f32x4;
typedef __attribute__((ext_vector_type(2))) float f32x2;
typedef __attribute__((ext_vector_type(4))) unsigned short u16x4;
typedef unsigned short u16;

__device__ __forceinline__ float rcp_(float x) { return __builtin_amdgcn_rcpf(x); }
__device__ __forceinline__ float ex2_(float x) { return __builtin_amdgcn_exp2f(x); }

__device__ __forceinline__ u16 bf16_rne(float x) {
    unsigned u = __float_as_uint(x);
    unsigned r = u + 0x7FFFu + ((u >> 16) & 1u);
    return (u16)(r >> 16);
}
__device__ __forceinline__ void split2(float x, u16& h, u16& l) {
    h = bf16_rne(x);
    float hf = __uint_as_float((unsigned)h << 16);
    l = bf16_rne(x - hf);
}
__device__ __forceinline__ void split4(float4 a, u16x4& h, u16x4& l) {
    u16 hh, ll;
    split2(a.x, hh, ll); h[0] = hh; l[0] = ll;
    split2(a.y, hh, ll); h[1] = hh; l[1] = ll;
    split2(a.z, hh, ll); h[2] = hh; l[2] = ll;
    split2(a.w, hh, ll); h[3] = hh; l[3] = ll;
}

// ---------------- presplit: q,k,Wq,Wk fp32 -> bf16 hi/lo planes (memory-bound) ----------
__global__ __launch_bounds__(256) void presplit(const float* __restrict__ q,
                                                const float* __restrict__ k,
                                                const float* __restrict__ Wq,
                                                const float* __restrict__ Wk,
                                                u16* __restrict__ q_hi, u16* __restrict__ q_lo,
                                                u16* __restrict__ k_hi, u16* __restrict__ k_lo,
                                                u16* __restrict__ w_hi, u16* __restrict__ w_lo) {
    const int NQ = 2048 * 512 / 4, NW = 256 * 512 / 4;  // float4 counts
    int idx = blockIdx.x * 256 + threadIdx.x;           // grid sized exactly
    const float* src; u16 *dh, *dl; int off;
    if (idx < NQ)             { src = q;  dh = q_hi; dl = q_lo; off = idx; }
    else if (idx < 2 * NQ)    { src = k;  dh = k_hi; dl = k_lo; off = idx - 2 * NQ + NQ; }
    else if (idx < 2 * NQ + NW) { src = Wq; dh = w_hi; dl = w_lo; off = idx - 2 * NQ; }
    else { src = Wk; dh = w_hi + 256 * 512; dl = w_lo + 256 * 512; off = idx - 2 * NQ - NW; }
    float4 v4 = ((const float4*)src)[off];
    u16x4 h, l;
    split4(v4, h, l);
    *(u16x4*)(dh + off * 4) = h;
    *(u16x4*)(dl + off * 4) = l;
}

// ---------------- vtrans: v[b][j][n] -> vt_hi/lo[b][n][j] bf16 planes -------------------
__global__ __launch_bounds__(256) void vtrans(const float* __restrict__ v,
                                              u16* __restrict__ vt_hi,
                                              u16* __restrict__ vt_lo) {
    __shared__ float ts[64][65];
    const int b = blockIdx.z;
    const int j0 = blockIdx.x * 64, n0 = blockIdx.y * 64;
    const int tid = threadIdx.x;
#pragma unroll
    for (int t = 0; t < 4; ++t) {
        int idx = t * 256 + tid;
        int j = idx >> 4, nq = idx & 15;
        float4 v4 = *(const float4*)(v + ((size_t)b * KVN + j0 + j) * VD_ + n0 + nq * 4);
        *(float4*)&ts[j][nq * 4] = v4;
    }
    __syncthreads();
#pragma unroll
    for (int t = 0; t < 4; ++t) {
        int idx = t * 256 + tid;
        int jq = idx & 15, n = idx >> 4;
        u16x4 h, l;
        u16 hh, ll;
#pragma unroll
        for (int e = 0; e < 4; ++e) {
            split2(ts[jq * 4 + e][n], hh, ll);
            h[e] = hh; l[e] = ll;
        }
        size_t off = ((size_t)b * VD_ + n0 + n) * KVN + j0 + jq * 4;
        *(u16x4*)(vt_hi + off) = h;
        *(u16x4*)(vt_lo + off) = l;
    }
}

// ---------------- proj: z=0 -> eqT[h][row] = exp2(qh'), z=1 -> ek[row][h] = exp2(kh') ---
// 32x32 tile, 4 waves as 2x2 of 16x16; presplit bf16 planes; 3-MFMA fp32 emulation.
// D-frag: col=lane&15, row=4*(lane>>4)+reg -> eqT store is a contiguous float4 along rows.
__global__ __launch_bounds__(256) void proj_mfma(const u16* __restrict__ q_hi, const u16* __restrict__ q_lo,
                                                 const u16* __restrict__ k_hi, const u16* __restrict__ k_lo,
                                                 const u16* __restrict__ w_hi, const u16* __restrict__ w_lo,
                                                 float* __restrict__ eqT, float* __restrict__ ek) {
    const int z = blockIdx.z;
    const u16* __restrict__ Ah_g = z ? k_hi : q_hi;
    const u16* __restrict__ Al_g = z ? k_lo : q_lo;
    const u16* __restrict__ Bh_g = w_hi + (size_t)z * H_ * QD_;
    const u16* __restrict__ Bl_g = w_lo + (size_t)z * H_ * QD_;
    __shared__ u16 Ash[4][32][8], Asl[4][32][8], Bsh[4][32][8], Bsl[4][32][8];
    const int tid = threadIdx.x;
    const int wave = tid >> 6, lane = tid & 63;
    const int fl = lane & 15, kg = lane >> 4;
    const int r0 = blockIdx.y * 32, c0 = blockIdx.x * 32;
    const int ar = 16 * (wave & 1), bc = 16 * (wave >> 1);
    const int frow = (tid & 127) >> 2, fkq = tid & 3, fsel = tid >> 7;
    f32x4 acc = {};
    for (int k0 = 0; k0 < QD_; k0 += 32) {
        __syncthreads();
        {
            const u16* as = (fsel ? Al_g : Ah_g) + (size_t)(r0 + frow) * QD_ + k0 + fkq * 8;
            u16* ad = fsel ? &Asl[fkq][frow][0] : &Ash[fkq][frow][0];
            *(uint4*)ad = *(const uint4*)as;
            const u16* bs = (fsel ? Bl_g : Bh_g) + (size_t)(c0 + frow) * QD_ + k0 + fkq * 8;
            u16* bd = fsel ? &Bsl[fkq][frow][0] : &Bsh[fkq][frow][0];
            *(uint4*)bd = *(const uint4*)bs;
        }
        __syncthreads();
        bf16x8 a_h = *(const bf16x8*)&Ash[kg][ar + fl][0];
        bf16x8 a_l = *(const bf16x8*)&Asl[kg][ar + fl][0];
        bf16x8 b_h = *(const bf16x8*)&Bsh[kg][bc + fl][0];
        bf16x8 b_l = *(const bf16x8*)&Bsl[kg][bc + fl][0];
        acc = __builtin_amdgcn_mfma_f32_16x16x32_bf16(a_h, b_h, acc, 0, 0, 0);
        acc = __builtin_amdgcn_mfma_f32_16x16x32_bf16(a_h, b_l, acc, 0, 0, 0);
        acc = __builtin_amdgcn_mfma_f32_16x16x32_bf16(a_l, b_h, acc, 0, 0, 0);
    }
    const float cs = 2.8853900817779268f;  // 2*log2(e)
    const int rg = kg * 4;
    if (z == 0) {
        // eqT[col][row..row+3] — contiguous float4
        float4 o = {ex2_(acc[0] * cs), ex2_(acc[1] * cs), ex2_(acc[2] * cs), ex2_(acc[3] * cs)};
        *(float4*)(eqT + (size_t)(c0 + bc + fl) * TOTR + r0 + ar + rg) = o;
    } else {
#pragma unroll
        for (int r = 0; r < 4; ++r)
            ek[(size_t)(r0 + ar + rg + r) * H_ + c0 + bc + fl] = ex2_(acc[r] * cs);
    }
}

// ---------------- scores: sc = -2 * sum_h wv[h] * rcp(1 + eq*ek) ------------------------
// (scores minus row-const sum(wv); softmax shift-invariant.)
// Packed-f32 over q-PAIRS (v_pk_fma_f32): per thread 2q(packed) x 2k; q from global eqT
// (16-lane-broadcast 128B loads, vmem pipe); only ek staged in LDS. 4-way rcp combine
// over h: 14 pk + 2 rcp per 8 evals.
__device__ __forceinline__ f32x2 col4(const f32x2* qp, float4 kc, float4 w4, f32x2 acc) {
    const f32x2 one = {1.0f, 1.0f};
    f32x2 d0 = __builtin_elementwise_fma(qp[0], (f32x2){kc.x, kc.x}, one);
    f32x2 d1 = __builtin_elementwise_fma(qp[1], (f32x2){kc.y, kc.y}, one);
    f32x2 d2 = __builtin_elementwise_fma(qp[2], (f32x2){kc.z, kc.z}, one);
    f32x2 d3 = __builtin_elementwise_fma(qp[3], (f32x2){kc.w, kc.w}, one);
    f32x2 ab = d0 * d1, cd = d2 * d3;
    f32x2 n1 = __builtin_elementwise_fma((f32x2){w4.y, w4.y}, d0, (f32x2){w4.x, w4.x} * d1);
    f32x2 n2 = __builtin_elementwise_fma((f32x2){w4.w, w4.w}, d2, (f32x2){w4.z, w4.z} * d3);
    f32x2 num = __builtin_elementwise_fma(n2, ab, n1 * cd);
    f32x2 den = ab * cd;
    f32x2 r = {rcp_(den.x), rcp_(den.y)};
    return __builtin_elementwise_fma(num, r, acc);
}

__global__ __launch_bounds__(256, 4) void scores_kernel(const float* __restrict__ eqT,
                                                        const float* __restrict__ ek,
                                                        const float* __restrict__ wv,
                                                        float* __restrict__ sc) {
    __shared__ float ks[32][68];
    const int b = blockIdx.z;
    const int i0 = blockIdx.y * 32, j0 = blockIdx.x * 32;
    const int tid = threadIdx.x;
    const int qg = tid & 15, kg = tid >> 4;  // q-rows: i0+2qg+{0,1}; k-cols: j0+2kg+{0,1}
    const int row0 = b * QN + i0 + 2 * qg;
    f32x2 acc0 = {0.f, 0.f}, acc1 = {0.f, 0.f};
    for (int h0 = 0; h0 < H_; h0 += 64) {
        __syncthreads();
#pragma unroll
        for (int t = 0; t < 2; ++t) {  // stage ek chunk: 32 k-rows x 64 h
            int idx = t * 256 + tid;
            int row = idx >> 4, c4 = idx & 15;
            *(float4*)&ks[row][c4 * 4] =
                *(const float4*)(ek + (size_t)(b * KVN + j0 + row) * H_ + h0 + c4 * 4);
        }
        __syncthreads();
#pragma unroll 8
        for (int hh = 0; hh < 64; hh += 4) {
            float4 w4 = *(const float4*)(wv + h0 + hh);  // uniform -> s_load
            f32x2 qp[4];
#pragma unroll
            for (int e = 0; e < 4; ++e)
                qp[e] = *(const f32x2*)(eqT + (size_t)(h0 + hh + e) * TOTR + row0);
            float4 kc0 = *(const float4*)&ks[2 * kg][hh];
            float4 kc1 = *(const float4*)&ks[2 * kg + 1][hh];
            acc0 = col4(qp, kc0, w4, acc0);
            acc1 = col4(qp, kc1, w4, acc1);
        }
    }
    f32x2 s0 = {-2.0f * acc0.x, -2.0f * acc1.x};  // row0,   cols 2kg,2kg+1
    f32x2 s1 = {-2.0f * acc0.y, -2.0f * acc1.y};  // row0+1, cols 2kg,2kg+1
    *(f32x2*)(sc + (size_t)row0 * KVN + j0 + 2 * kg) = s0;
    *(f32x2*)(sc + (size_t)(row0 + 1) * KVN + j0 + 2 * kg) = s1;
}

// ---------------- softmax (in-place fp32) + bf16 hi/lo plane emit -----------------------
__global__ __launch_bounds__(256) void softmax_kernel(float* __restrict__ attn,
                                                      u16* __restrict__ at_hi,
                                                      u16* __restrict__ at_lo) {
    int row = blockIdx.x;
    int tid = threadIdx.x;
    float* p = attn + (size_t)row * KVN;
    float x0 = p[tid], x1 = p[tid + 256];
    float m = fmaxf(x0, x1);
#pragma unroll
    for (int d = 1; d < 64; d <<= 1) m = fmaxf(m, __shfl_xor(m, d));
    __shared__ float redm[4], reds[4];
    int wave = tid >> 6, lane = tid & 63;
    if (lane == 0) redm[wave] = m;
    __syncthreads();
    m = fmaxf(fmaxf(redm[0], redm[1]), fmaxf(redm[2], redm[3]));
    float e0 = __expf(x0 - m), e1 = __expf(x1 - m);
    float s = e0 + e1;
#pragma unroll
    for (int d = 1; d < 64; d <<= 1) s += __shfl_xor(s, d);
    if (lane == 0) reds[wave] = s;
    __syncthreads();
    s = reds[0] + reds[1] + reds[2] + reds[3];
    float inv = rcp_(s);
    float r0v = e0 * inv, r1v = e1 * inv;
    p[tid] = r0v;
    p[tid + 256] = r1v;
    u16 h, l;
    size_t base = (size_t)row * KVN;
    split2(r0v, h, l);
    at_hi[base + tid] = h; at_lo[base + tid] = l;
    split2(r1v, h, l);
    at_hi[base + tid + 256] = h; at_lo[base + tid + 256] = l;
}

// ---------------- out: out[b][i][n] = sum_j attn[b][i][j] * v[b][j][n] ------------------
// D[n][i] via A=vt (n-rows, j-contig), B=at (i-rows, j-contig); float4 stores along n.
__global__ __launch_bounds__(256) void out_mfma(const u16* __restrict__ vt_hi, const u16* __restrict__ vt_lo,
                                                const u16* __restrict__ at_hi, const u16* __restrict__ at_lo,
                                                float* __restrict__ out) {
    const int b = blockIdx.z;
    const u16* __restrict__ Ah_g = vt_hi + (size_t)b * VD_ * KVN;
    const u16* __restrict__ Al_g = vt_lo + (size_t)b * VD_ * KVN;
    const u16* __restrict__ Bh_g = at_hi + (size_t)b * QN * KVN;
    const u16* __restrict__ Bl_g = at_lo + (size_t)b * QN * KVN;
    float* __restrict__ outb = out + (size_t)b * QN * VD_;
    __shared__ u16 Ash[4][32][8], Asl[4][32][8], Bsh[4][32][8], Bsl[4][32][8];
    const int tid = threadIdx.x;
    const int wave = tid >> 6, lane = tid & 63;
    const int fl = lane & 15, kg = lane >> 4;
    const int r0 = blockIdx.y * 32;  // n-tile
    const int c0 = blockIdx.x * 32;  // i-tile
    const int ar = 16 * (wave & 1), bc = 16 * (wave >> 1);
    const int frow = (tid & 127) >> 2, fkq = tid & 3, fsel = tid >> 7;
    f32x4 acc = {};
    for (int k0 = 0; k0 < KVN; k0 += 32) {
        __syncthreads();
        {
            const u16* as = (fsel ? Al_g : Ah_g) + (size_t)(r0 + frow) * KVN + k0 + fkq * 8;
            u16* ad = fsel ? &Asl[fkq][frow][0] : &Ash[fkq][frow][0];
            *(uint4*)ad = *(const uint4*)as;
            const u16* bs = (fsel ? Bl_g : Bh_g) + (size_t)(c0 + frow) * KVN + k0 + fkq * 8;
            u16* bd = fsel ? &Bsl[fkq][frow][0] : &Bsh[fkq][frow][0];
            *(uint4*)bd = *(const uint4*)bs;
        }
        __syncthreads();
        bf16x8 a_h = *(const bf16x8*)&Ash[kg][ar + fl][0];
        bf16x8 a_l = *(const bf16x8*)&Asl[kg][ar + fl][0];
        bf16x8 b_h = *(const bf16x8*)&Bsh[kg][bc + fl][0];
        bf16x8 b_l = *(const bf16x8*)&Bsl[kg][bc + fl][0];
        acc = __builtin_amdgcn_mfma_f32_16x16x32_bf16(a_h, b_h, acc, 0, 0, 0);
        acc = __builtin_amdgcn_mfma_f32_16x16x32_bf16(a_h, b_l, acc, 0, 0, 0);
        acc = __builtin_amdgcn_mfma_f32_16x16x32_bf16(a_l, b_h, acc, 0, 0, 0);
    }
    const int rg = kg * 4;
    float4 o = {acc[0], acc[1], acc[2], acc[3]};
    *(float4*)(outb + (size_t)(c0 + bc + fl) * VD_ + r0 + ar + rg) = o;
}

extern "C" void kernel_launch(void* const* d_in, const int* in_sizes, int n_in,
                              void* d_out, int out_size, void* d_ws, size_t ws_size,
                              hipStream_t stream) {
    const float* q  = (const float*)d_in[0];
    const float* k  = (const float*)d_in[1];
    const float* v  = (const float*)d_in[2];
    const float* Wq = (const float*)d_in[3];
    const float* Wk = (const float*)d_in[4];
    const float* wv = (const float*)d_in[5];
    float* out  = (float*)d_out;                   // [B, QN, VD]
    float* attn = out + (size_t)B_ * QN * VD_;     // [B, QN, KVN]

    float* eqT = (float*)d_ws;                     // [H][2048] f32  (= exp2(qh'), transposed)
    float* ek  = eqT + H_ * TOTR;                  // [2048][H] f32
    u16* q_hi = (u16*)(ek + TOTR * H_);            // [2048][512] u16 each
    u16* q_lo = q_hi + 2048 * 512;
    u16* k_hi = q_lo + 2048 * 512;
    u16* k_lo = k_hi + 2048 * 512;
    u16* w_hi = k_lo + 2048 * 512;                 // [512][512] (Wq rows 0-255, Wk 256-511)
    u16* w_lo = w_hi + 512 * 512;
    u16* vt_hi = w_lo + 512 * 512;                 // [4][256][512]
    u16* vt_lo = vt_hi + (size_t)B_ * VD_ * KVN;
    u16* at_hi = q_hi;                             // alias: q planes dead after proj
    u16* at_lo = q_lo;

    presplit<<<2304, 256, 0, stream>>>(q, k, Wq, Wk, q_hi, q_lo, k_hi, k_lo, w_hi, w_lo);
    vtrans<<<dim3(KVN / 64, VD_ / 64, B_), 256, 0, stream>>>(v, vt_hi, vt_lo);
    proj_mfma<<<dim3(H_ / 32, 2048 / 32, 2), 256, 0, stream>>>(q_hi, q_lo, k_hi, k_lo,
                                                               w_hi, w_lo, eqT, ek);
    scores_kernel<<<dim3(KVN / 32, QN / 32, B_), 256, 0, stream>>>(eqT, ek, wv, attn);
    softmax_kernel<<<B_ * QN, 256, 0, stream>>>(attn, at_hi, at_lo);
    out_mfma<<<dim3(QN / 32, VD_ / 32, B_), 256, 0, stream>>>(vt_hi, vt_lo, at_hi, at_lo, out);
}

// Round 9
// 69.886 us; speedup vs baseline: 1.3314x; 1.3314x over previous
//
#include <hip/hip_runtime.h>

#define B_ 4
#define QN 512
#define KVN 512
#define QD_ 512
#define H_ 256
#define VD_ 256
#define TOTR 2048  // B_*QN

typedef __attribute__((ext_vector_type(8))) short bf16x8;
typedef __attribute__((ext_vector_type(4))) float f32x4;
typedef __attribute__((ext_vector_type(2))) float f32x2;
typedef __attribute__((ext_vector_type(4))) unsigned short u16x4;
typedef unsigned short u16;

__device__ __forceinline__ float rcp_(float x) { return __builtin_amdgcn_rcpf(x); }
__device__ __forceinline__ float ex2_(float x) { return __builtin_amdgcn_exp2f(x); }

__device__ __forceinline__ u16 bf16_rne(float x) {
    unsigned u = __float_as_uint(x);
    unsigned r = u + 0x7FFFu + ((u >> 16) & 1u);
    return (u16)(r >> 16);
}
__device__ __forceinline__ void split2(float x, u16& h, u16& l) {
    h = bf16_rne(x);
    float hf = __uint_as_float((unsigned)h << 16);
    l = bf16_rne(x - hf);
}
__device__ __forceinline__ void split4(float4 a, u16x4& h, u16x4& l) {
    u16 hh, ll;
    split2(a.x, hh, ll); h[0] = hh; l[0] = ll;
    split2(a.y, hh, ll); h[1] = hh; l[1] = ll;
    split2(a.z, hh, ll); h[2] = hh; l[2] = ll;
    split2(a.w, hh, ll); h[3] = hh; l[3] = ll;
}

// ---------------- presplit: q,k,Wq,Wk fp32 -> bf16 hi/lo planes (memory-bound) ----------
__global__ __launch_bounds__(256) void presplit(const float* __restrict__ q,
                                                const float* __restrict__ k,
                                                const float* __restrict__ Wq,
                                                const float* __restrict__ Wk,
                                                u16* __restrict__ q_hi, u16* __restrict__ q_lo,
                                                u16* __restrict__ k_hi, u16* __restrict__ k_lo,
                                                u16* __restrict__ w_hi, u16* __restrict__ w_lo) {
    const int NQ = 2048 * 512 / 4, NW = 256 * 512 / 4;  // float4 counts
    int idx = blockIdx.x * 256 + threadIdx.x;           // grid sized exactly
    const float* src; u16 *dh, *dl; int off;
    if (idx < NQ)             { src = q;  dh = q_hi; dl = q_lo; off = idx; }
    else if (idx < 2 * NQ)    { src = k;  dh = k_hi; dl = k_lo; off = idx - 2 * NQ + NQ; }
    else if (idx < 2 * NQ + NW) { src = Wq; dh = w_hi; dl = w_lo; off = idx - 2 * NQ; }
    else { src = Wk; dh = w_hi + 256 * 512; dl = w_lo + 256 * 512; off = idx - 2 * NQ - NW; }
    float4 v4 = ((const float4*)src)[off];
    u16x4 h, l;
    split4(v4, h, l);
    *(u16x4*)(dh + off * 4) = h;
    *(u16x4*)(dl + off * 4) = l;
}

// ---------------- vtrans: v[b][j][n] -> vt_hi/lo[b][n][j] bf16 planes -------------------
__global__ __launch_bounds__(256) void vtrans(const float* __restrict__ v,
                                              u16* __restrict__ vt_hi,
                                              u16* __restrict__ vt_lo) {
    __shared__ float ts[64][65];
    const int b = blockIdx.z;
    const int j0 = blockIdx.x * 64, n0 = blockIdx.y * 64;
    const int tid = threadIdx.x;
#pragma unroll
    for (int t = 0; t < 4; ++t) {
        int idx = t * 256 + tid;
        int j = idx >> 4, nq = idx & 15;
        float4 v4 = *(const float4*)(v + ((size_t)b * KVN + j0 + j) * VD_ + n0 + nq * 4);
        *(float4*)&ts[j][nq * 4] = v4;
    }
    __syncthreads();
#pragma unroll
    for (int t = 0; t < 4; ++t) {
        int idx = t * 256 + tid;
        int jq = idx & 15, n = idx >> 4;
        u16x4 h, l;
        u16 hh, ll;
#pragma unroll
        for (int e = 0; e < 4; ++e) {
            split2(ts[jq * 4 + e][n], hh, ll);
            h[e] = hh; l[e] = ll;
        }
        size_t off = ((size_t)b * VD_ + n0 + n) * KVN + j0 + jq * 4;
        *(u16x4*)(vt_hi + off) = h;
        *(u16x4*)(vt_lo + off) = l;
    }
}

// ---------------- proj: z=0 -> eqT[h][row] = exp2(qh'), z=1 -> ek[row][h] = exp2(kh') ---
// 32x32 tile, 4 waves as 2x2 of 16x16; presplit bf16 planes; 3-MFMA fp32 emulation.
// D-frag: col=lane&15, row=4*(lane>>4)+reg -> eqT store is a contiguous float4 along rows.
__global__ __launch_bounds__(256) void proj_mfma(const u16* __restrict__ q_hi, const u16* __restrict__ q_lo,
                                                 const u16* __restrict__ k_hi, const u16* __restrict__ k_lo,
                                                 const u16* __restrict__ w_hi, const u16* __restrict__ w_lo,
                                                 float* __restrict__ eqT, float* __restrict__ ek) {
    const int z = blockIdx.z;
    const u16* __restrict__ Ah_g = z ? k_hi : q_hi;
    const u16* __restrict__ Al_g = z ? k_lo : q_lo;
    const u16* __restrict__ Bh_g = w_hi + (size_t)z * H_ * QD_;
    const u16* __restrict__ Bl_g = w_lo + (size_t)z * H_ * QD_;
    __shared__ u16 Ash[4][32][8], Asl[4][32][8], Bsh[4][32][8], Bsl[4][32][8];
    const int tid = threadIdx.x;
    const int wave = tid >> 6, lane = tid & 63;
    const int fl = lane & 15, kg = lane >> 4;
    const int r0 = blockIdx.y * 32, c0 = blockIdx.x * 32;
    const int ar = 16 * (wave & 1), bc = 16 * (wave >> 1);
    const int frow = (tid & 127) >> 2, fkq = tid & 3, fsel = tid >> 7;
    f32x4 acc = {};
    for (int k0 = 0; k0 < QD_; k0 += 32) {
        __syncthreads();
        {
            const u16* as = (fsel ? Al_g : Ah_g) + (size_t)(r0 + frow) * QD_ + k0 + fkq * 8;
            u16* ad = fsel ? &Asl[fkq][frow][0] : &Ash[fkq][frow][0];
            *(uint4*)ad = *(const uint4*)as;
            const u16* bs = (fsel ? Bl_g : Bh_g) + (size_t)(c0 + frow) * QD_ + k0 + fkq * 8;
            u16* bd = fsel ? &Bsl[fkq][frow][0] : &Bsh[fkq][frow][0];
            *(uint4*)bd = *(const uint4*)bs;
        }
        __syncthreads();
        bf16x8 a_h = *(const bf16x8*)&Ash[kg][ar + fl][0];
        bf16x8 a_l = *(const bf16x8*)&Asl[kg][ar + fl][0];
        bf16x8 b_h = *(const bf16x8*)&Bsh[kg][bc + fl][0];
        bf16x8 b_l = *(const bf16x8*)&Bsl[kg][bc + fl][0];
        acc = __builtin_amdgcn_mfma_f32_16x16x32_bf16(a_h, b_h, acc, 0, 0, 0);
        acc = __builtin_amdgcn_mfma_f32_16x16x32_bf16(a_h, b_l, acc, 0, 0, 0);
        acc = __builtin_amdgcn_mfma_f32_16x16x32_bf16(a_l, b_h, acc, 0, 0, 0);
    }
    const float cs = 2.8853900817779268f;  // 2*log2(e)
    const int rg = kg * 4;
    if (z == 0) {
        // eqT[col][row..row+3] — contiguous float4
        float4 o = {ex2_(acc[0] * cs), ex2_(acc[1] * cs), ex2_(acc[2] * cs), ex2_(acc[3] * cs)};
        *(float4*)(eqT + (size_t)(c0 + bc + fl) * TOTR + r0 + ar + rg) = o;
    } else {
#pragma unroll
        for (int r = 0; r < 4; ++r)
            ek[(size_t)(r0 + ar + rg + r) * H_ + c0 + bc + fl] = ex2_(acc[r] * cs);
    }
}

// ---------------- scores: sc = -2 * sum_h wv[h] * rcp(1 + eq*ek) ------------------------
// (scores minus row-const sum(wv); softmax shift-invariant.)
// Packed-f32 over q-PAIRS; BOTH operands LDS-staged with conflict-free layouts:
//   qs2[64][16] f32x2: write 128B-contig; read qs2[hh+e][qg] b64 covers 32 banks + bcast.
//   ks [32][68] f32:   read b128, 4 row-addrs/wave, disjoint banks.
// 4-way rcp combine over h: 14 pk + 2 rcp per 8 packed-evals.
__device__ __forceinline__ f32x2 col4(const f32x2* qp, float4 kc, float4 w4, f32x2 acc) {
    const f32x2 one = {1.0f, 1.0f};
    f32x2 d0 = __builtin_elementwise_fma(qp[0], (f32x2){kc.x, kc.x}, one);
    f32x2 d1 = __builtin_elementwise_fma(qp[1], (f32x2){kc.y, kc.y}, one);
    f32x2 d2 = __builtin_elementwise_fma(qp[2], (f32x2){kc.z, kc.z}, one);
    f32x2 d3 = __builtin_elementwise_fma(qp[3], (f32x2){kc.w, kc.w}, one);
    f32x2 ab = d0 * d1, cd = d2 * d3;
    f32x2 n1 = __builtin_elementwise_fma((f32x2){w4.y, w4.y}, d0, (f32x2){w4.x, w4.x} * d1);
    f32x2 n2 = __builtin_elementwise_fma((f32x2){w4.w, w4.w}, d2, (f32x2){w4.z, w4.z} * d3);
    f32x2 num = __builtin_elementwise_fma(n2, ab, n1 * cd);
    f32x2 den = ab * cd;
    f32x2 r = {rcp_(den.x), rcp_(den.y)};
    return __builtin_elementwise_fma(num, r, acc);
}

__global__ __launch_bounds__(256, 4) void scores_kernel(const float* __restrict__ eqT,
                                                        const float* __restrict__ ek,
                                                        const float* __restrict__ wv,
                                                        float* __restrict__ sc) {
    __shared__ f32x2 qs2[64][16];   // [h-in-chunk][q-pair]
    __shared__ float ks[32][68];    // [k-row][h-in-chunk]
    const int b = blockIdx.z;
    const int i0 = blockIdx.y * 32, j0 = blockIdx.x * 32;
    const int tid = threadIdx.x;
    const int qg = tid & 15, kg = tid >> 4;  // q-rows: i0+2qg+{0,1}; k-cols: j0+2kg+{0,1}
    const int row0 = b * QN + i0 + 2 * qg;
    f32x2 acc0 = {0.f, 0.f}, acc1 = {0.f, 0.f};
    for (int h0 = 0; h0 < H_; h0 += 64) {
        __syncthreads();
#pragma unroll
        for (int t = 0; t < 4; ++t) {  // stage q-pairs: 64 h x 16 pairs (1024 writes)
            int idx = t * 256 + tid;
            int hq = idx >> 4, pr = idx & 15;  // 16 lanes -> 128B contiguous global
            qs2[hq][pr] = *(const f32x2*)(eqT + (size_t)(h0 + hq) * TOTR + b * QN + i0 + pr * 2);
        }
#pragma unroll
        for (int t = 0; t < 2; ++t) {  // stage ek chunk: 32 k-rows x 64 h (512 float4s)
            int idx = t * 256 + tid;
            int row = idx >> 4, c4 = idx & 15;
            *(float4*)&ks[row][c4 * 4] =
                *(const float4*)(ek + (size_t)(b * KVN + j0 + row) * H_ + h0 + c4 * 4);
        }
        __syncthreads();
#pragma unroll 8
        for (int hh = 0; hh < 64; hh += 4) {
            float4 w4 = *(const float4*)(wv + h0 + hh);  // uniform -> s_load
            f32x2 qp[4];
#pragma unroll
            for (int e = 0; e < 4; ++e) qp[e] = qs2[hh + e][qg];
            float4 kc0 = *(const float4*)&ks[2 * kg][hh];
            float4 kc1 = *(const float4*)&ks[2 * kg + 1][hh];
            acc0 = col4(qp, kc0, w4, acc0);
            acc1 = col4(qp, kc1, w4, acc1);
        }
    }
    f32x2 s0 = {-2.0f * acc0.x, -2.0f * acc1.x};  // row0,   cols 2kg,2kg+1
    f32x2 s1 = {-2.0f * acc0.y, -2.0f * acc1.y};  // row0+1, cols 2kg,2kg+1
    *(f32x2*)(sc + (size_t)row0 * KVN + j0 + 2 * kg) = s0;
    *(f32x2*)(sc + (size_t)(row0 + 1) * KVN + j0 + 2 * kg) = s1;
}

// ---------------- softmax (in-place fp32) + bf16 hi/lo plane emit -----------------------
__global__ __launch_bounds__(256) void softmax_kernel(float* __restrict__ attn,
                                                      u16* __restrict__ at_hi,
                                                      u16* __restrict__ at_lo) {
    int row = blockIdx.x;
    int tid = threadIdx.x;
    float* p = attn + (size_t)row * KVN;
    float x0 = p[tid], x1 = p[tid + 256];
    float m = fmaxf(x0, x1);
#pragma unroll
    for (int d = 1; d < 64; d <<= 1) m = fmaxf(m, __shfl_xor(m, d));
    __shared__ float redm[4], reds[4];
    int wave = tid >> 6, lane = tid & 63;
    if (lane == 0) redm[wave] = m;
    __syncthreads();
    m = fmaxf(fmaxf(redm[0], redm[1]), fmaxf(redm[2], redm[3]));
    float e0 = __expf(x0 - m), e1 = __expf(x1 - m);
    float s = e0 + e1;
#pragma unroll
    for (int d = 1; d < 64; d <<= 1) s += __shfl_xor(s, d);
    if (lane == 0) reds[wave] = s;
    __syncthreads();
    s = reds[0] + reds[1] + reds[2] + reds[3];
    float inv = rcp_(s);
    float r0v = e0 * inv, r1v = e1 * inv;
    p[tid] = r0v;
    p[tid + 256] = r1v;
    u16 h, l;
    size_t base = (size_t)row * KVN;
    split2(r0v, h, l);
    at_hi[base + tid] = h; at_lo[base + tid] = l;
    split2(r1v, h, l);
    at_hi[base + tid + 256] = h; at_lo[base + tid + 256] = l;
}

// ---------------- out: out[b][i][n] = sum_j attn[b][i][j] * v[b][j][n] ------------------
// D[n][i] via A=vt (n-rows, j-contig), B=at (i-rows, j-contig); float4 stores along n.
__global__ __launch_bounds__(256) void out_mfma(const u16* __restrict__ vt_hi, const u16* __restrict__ vt_lo,
                                                const u16* __restrict__ at_hi, const u16* __restrict__ at_lo,
                                                float* __restrict__ out) {
    const int b = blockIdx.z;
    const u16* __restrict__ Ah_g = vt_hi + (size_t)b * VD_ * KVN;
    const u16* __restrict__ Al_g = vt_lo + (size_t)b * VD_ * KVN;
    const u16* __restrict__ Bh_g = at_hi + (size_t)b * QN * KVN;
    const u16* __restrict__ Bl_g = at_lo + (size_t)b * QN * KVN;
    float* __restrict__ outb = out + (size_t)b * QN * VD_;
    __shared__ u16 Ash[4][32][8], Asl[4][32][8], Bsh[4][32][8], Bsl[4][32][8];
    const int tid = threadIdx.x;
    const int wave = tid >> 6, lane = tid & 63;
    const int fl = lane & 15, kg = lane >> 4;
    const int r0 = blockIdx.y * 32;  // n-tile
    const int c0 = blockIdx.x * 32;  // i-tile
    const int ar = 16 * (wave & 1), bc = 16 * (wave >> 1);
    const int frow = (tid & 127) >> 2, fkq = tid & 3, fsel = tid >> 7;
    f32x4 acc = {};
    for (int k0 = 0; k0 < KVN; k0 += 32) {
        __syncthreads();
        {
            const u16* as = (fsel ? Al_g : Ah_g) + (size_t)(r0 + frow) * KVN + k0 + fkq * 8;
            u16* ad = fsel ? &Asl[fkq][frow][0] : &Ash[fkq][frow][0];
            *(uint4*)ad = *(const uint4*)as;
            const u16* bs = (fsel ? Bl_g : Bh_g) + (size_t)(c0 + frow) * KVN + k0 + fkq * 8;
            u16* bd = fsel ? &Bsl[fkq][frow][0] : &Bsh[fkq][frow][0];
            *(uint4*)bd = *(const uint4*)bs;
        }
        __syncthreads();
        bf16x8 a_h = *(const bf16x8*)&Ash[kg][ar + fl][0];
        bf16x8 a_l = *(const bf16x8*)&Asl[kg][ar + fl][0];
        bf16x8 b_h = *(const bf16x8*)&Bsh[kg][bc + fl][0];
        bf16x8 b_l = *(const bf16x8*)&Bsl[kg][bc + fl][0];
        acc = __builtin_amdgcn_mfma_f32_16x16x32_bf16(a_h, b_h, acc, 0, 0, 0);
        acc = __builtin_amdgcn_mfma_f32_16x16x32_bf16(a_h, b_l, acc, 0, 0, 0);
        acc = __builtin_amdgcn_mfma_f32_16x16x32_bf16(a_l, b_h, acc, 0, 0, 0);
    }
    const int rg = kg * 4;
    float4 o = {acc[0], acc[1], acc[2], acc[3]};
    *(float4*)(outb + (size_t)(c0 + bc + fl) * VD_ + r0 + ar + rg) = o;
}

extern "C" void kernel_launch(void* const* d_in, const int* in_sizes, int n_in,
                              void* d_out, int out_size, void* d_ws, size_t ws_size,
                              hipStream_t stream) {
    const float* q  = (const float*)d_in[0];
    const float* k  = (const float*)d_in[1];
    const float* v  = (const float*)d_in[2];
    const float* Wq = (const float*)d_in[3];
    const float* Wk = (const float*)d_in[4];
    const float* wv = (const float*)d_in[5];
    float* out  = (float*)d_out;                   // [B, QN, VD]
    float* attn = out + (size_t)B_ * QN * VD_;     // [B, QN, KVN]

    float* eqT = (float*)d_ws;                     // [H][2048] f32  (= exp2(qh'), transposed)
    float* ek  = eqT + H_ * TOTR;                  // [2048][H] f32
    u16* q_hi = (u16*)(ek + TOTR * H_);            // [2048][512] u16 each
    u16* q_lo = q_hi + 2048 * 512;
    u16* k_hi = q_lo + 2048 * 512;
    u16* k_lo = k_hi + 2048 * 512;
    u16* w_hi = k_lo + 2048 * 512;                 // [512][512] (Wq rows 0-255, Wk 256-511)
    u16* w_lo = w_hi + 512 * 512;
    u16* vt_hi = w_lo + 512 * 512;                 // [4][256][512]
    u16* vt_lo = vt_hi + (size_t)B_ * VD_ * KVN;
    u16* at_hi = q_hi;                             // alias: q planes dead after proj
    u16* at_lo = q_lo;

    presplit<<<2304, 256, 0, stream>>>(q, k, Wq, Wk, q_hi, q_lo, k_hi, k_lo, w_hi, w_lo);
    vtrans<<<dim3(KVN / 64, VD_ / 64, B_), 256, 0, stream>>>(v, vt_hi, vt_lo);
    proj_mfma<<<dim3(H_ / 32, 2048 / 32, 2), 256, 0, stream>>>(q_hi, q_lo, k_hi, k_lo,
                                                               w_hi, w_lo, eqT, ek);
    scores_kernel<<<dim3(KVN / 32, QN / 32, B_), 256, 0, stream>>>(eqT, ek, wv, attn);
    softmax_kernel<<<B_ * QN, 256, 0, stream>>>(attn, at_hi, at_lo);
    out_mfma<<<dim3(QN / 32, VD_ / 32, B_), 256, 0, stream>>>(vt_hi, vt_lo, at_hi, at_lo, out);
}

// Round 10
// 67.201 us; speedup vs baseline: 1.3846x; 1.0399x over previous
//
#include <hip/hip_runtime.h>

#define B_ 4
#define QN 512
#define KVN 512
#define QD_ 512
#define H_ 256
#define VD_ 256
#define TOTR 2048  // B_*QN

typedef __attribute__((ext_vector_type(8))) short bf16x8;
typedef __attribute__((ext_vector_type(4))) float f32x4;
typedef __attribute__((ext_vector_type(2))) float f32x2;
typedef __attribute__((ext_vector_type(4))) unsigned short u16x4;
typedef unsigned short u16;

__device__ __forceinline__ float rcp_(float x) { return __builtin_amdgcn_rcpf(x); }
__device__ __forceinline__ float ex2_(float x) { return __builtin_amdgcn_exp2f(x); }

__device__ __forceinline__ u16 bf16_rne(float x) {
    unsigned u = __float_as_uint(x);
    unsigned r = u + 0x7FFFu + ((u >> 16) & 1u);
    return (u16)(r >> 16);
}
__device__ __forceinline__ void split2(float x, u16& h, u16& l) {
    h = bf16_rne(x);
    float hf = __uint_as_float((unsigned)h << 16);
    l = bf16_rne(x - hf);
}
__device__ __forceinline__ void split4(float4 a, u16x4& h, u16x4& l) {
    u16 hh, ll;
    split2(a.x, hh, ll); h[0] = hh; l[0] = ll;
    split2(a.y, hh, ll); h[1] = hh; l[1] = ll;
    split2(a.z, hh, ll); h[2] = hh; l[2] = ll;
    split2(a.w, hh, ll); h[3] = hh; l[3] = ll;
}

// ---------------- prep: fused presplit (blocks 0..2303) + vtrans (blocks 2304..2431) ----
__global__ __launch_bounds__(256) void prep(const float* __restrict__ q,
                                            const float* __restrict__ k,
                                            const float* __restrict__ Wq,
                                            const float* __restrict__ Wk,
                                            const float* __restrict__ v,
                                            u16* __restrict__ q_hi, u16* __restrict__ q_lo,
                                            u16* __restrict__ k_hi, u16* __restrict__ k_lo,
                                            u16* __restrict__ w_hi, u16* __restrict__ w_lo,
                                            u16* __restrict__ vt_hi, u16* __restrict__ vt_lo) {
    __shared__ float ts[64][65];
    const int tid = threadIdx.x;
    if (blockIdx.x < 2304) {  // presplit: q,k,Wq,Wk -> bf16 hi/lo planes
        const int NQ = 2048 * 512 / 4, NW = 256 * 512 / 4;
        int idx = blockIdx.x * 256 + tid;
        const float* src; u16 *dh, *dl; int off;
        if (idx < NQ)               { src = q;  dh = q_hi; dl = q_lo; off = idx; }
        else if (idx < 2 * NQ)      { src = k;  dh = k_hi; dl = k_lo; off = idx - NQ; }
        else if (idx < 2 * NQ + NW) { src = Wq; dh = w_hi; dl = w_lo; off = idx - 2 * NQ; }
        else { src = Wk; dh = w_hi + 256 * 512; dl = w_lo + 256 * 512; off = idx - 2 * NQ - NW; }
        float4 v4 = ((const float4*)src)[off];
        u16x4 h, l;
        split4(v4, h, l);
        *(u16x4*)(dh + off * 4) = h;
        *(u16x4*)(dl + off * 4) = l;
    } else {  // vtrans: v[b][j][n] -> vt_hi/lo[b][n][j]
        int bid = blockIdx.x - 2304;  // 8 j-tiles x 4 n-tiles x 4 b
        int j0 = (bid & 7) * 64, n0 = ((bid >> 3) & 3) * 64, b = bid >> 5;
#pragma unroll
        for (int t = 0; t < 4; ++t) {
            int idx = t * 256 + tid;
            int j = idx >> 4, nq = idx & 15;
            float4 v4 = *(const float4*)(v + ((size_t)b * KVN + j0 + j) * VD_ + n0 + nq * 4);
            *(float4*)&ts[j][nq * 4] = v4;
        }
        __syncthreads();
#pragma unroll
        for (int t = 0; t < 4; ++t) {
            int idx = t * 256 + tid;
            int jq = idx & 15, n = idx >> 4;
            u16x4 h, l;
            u16 hh, ll;
#pragma unroll
            for (int e = 0; e < 4; ++e) {
                split2(ts[jq * 4 + e][n], hh, ll);
                h[e] = hh; l[e] = ll;
            }
            size_t off = ((size_t)b * VD_ + n0 + n) * KVN + j0 + jq * 4;
            *(u16x4*)(vt_hi + off) = h;
            *(u16x4*)(vt_lo + off) = l;
        }
    }
}

// ---------------- proj: z=0 -> eqT[h][row] = exp2(qh'), z=1 -> ek[row][h] = exp2(kh') ---
__global__ __launch_bounds__(256) void proj_mfma(const u16* __restrict__ q_hi, const u16* __restrict__ q_lo,
                                                 const u16* __restrict__ k_hi, const u16* __restrict__ k_lo,
                                                 const u16* __restrict__ w_hi, const u16* __restrict__ w_lo,
                                                 float* __restrict__ eqT, float* __restrict__ ek) {
    const int z = blockIdx.z;
    const u16* __restrict__ Ah_g = z ? k_hi : q_hi;
    const u16* __restrict__ Al_g = z ? k_lo : q_lo;
    const u16* __restrict__ Bh_g = w_hi + (size_t)z * H_ * QD_;
    const u16* __restrict__ Bl_g = w_lo + (size_t)z * H_ * QD_;
    __shared__ u16 Ash[4][32][8], Asl[4][32][8], Bsh[4][32][8], Bsl[4][32][8];
    const int tid = threadIdx.x;
    const int wave = tid >> 6, lane = tid & 63;
    const int fl = lane & 15, kg = lane >> 4;
    const int r0 = blockIdx.y * 32, c0 = blockIdx.x * 32;
    const int ar = 16 * (wave & 1), bc = 16 * (wave >> 1);
    const int frow = (tid & 127) >> 2, fkq = tid & 3, fsel = tid >> 7;
    f32x4 acc = {};
    for (int k0 = 0; k0 < QD_; k0 += 32) {
        __syncthreads();
        {
            const u16* as = (fsel ? Al_g : Ah_g) + (size_t)(r0 + frow) * QD_ + k0 + fkq * 8;
            u16* ad = fsel ? &Asl[fkq][frow][0] : &Ash[fkq][frow][0];
            *(uint4*)ad = *(const uint4*)as;
            const u16* bs = (fsel ? Bl_g : Bh_g) + (size_t)(c0 + frow) * QD_ + k0 + fkq * 8;
            u16* bd = fsel ? &Bsl[fkq][frow][0] : &Bsh[fkq][frow][0];
            *(uint4*)bd = *(const uint4*)bs;
        }
        __syncthreads();
        bf16x8 a_h = *(const bf16x8*)&Ash[kg][ar + fl][0];
        bf16x8 a_l = *(const bf16x8*)&Asl[kg][ar + fl][0];
        bf16x8 b_h = *(const bf16x8*)&Bsh[kg][bc + fl][0];
        bf16x8 b_l = *(const bf16x8*)&Bsl[kg][bc + fl][0];
        acc = __builtin_amdgcn_mfma_f32_16x16x32_bf16(a_h, b_h, acc, 0, 0, 0);
        acc = __builtin_amdgcn_mfma_f32_16x16x32_bf16(a_h, b_l, acc, 0, 0, 0);
        acc = __builtin_amdgcn_mfma_f32_16x16x32_bf16(a_l, b_h, acc, 0, 0, 0);
    }
    const float cs = 2.8853900817779268f;  // 2*log2(e)
    const int rg = kg * 4;
    if (z == 0) {
        float4 o = {ex2_(acc[0] * cs), ex2_(acc[1] * cs), ex2_(acc[2] * cs), ex2_(acc[3] * cs)};
        *(float4*)(eqT + (size_t)(c0 + bc + fl) * TOTR + r0 + ar + rg) = o;
    } else {
#pragma unroll
        for (int r = 0; r < 4; ++r)
            ek[(size_t)(r0 + ar + rg + r) * H_ + c0 + bc + fl] = ex2_(acc[r] * cs);
    }
}

// ---------------- scores v3: partial over 64 h -> scpart[hs] -----------------------------
// sc_part = -2 * sum_{h in chunk} wv[h] * rcp(1 + eq*ek).  64q x 64k tile, 4q x 4k per
// thread (2 q-pairs packed), h-split=4 across blockIdx.z.  One stage, no K-loop barriers.
// LDS: qs[64h][32 qpairs] f32x2 (b128 read = both pairs, 4 addrs/wave broadcast);
//      ks[64k][68] f32 (b128 read, 2-way bank alias = free).
__device__ __forceinline__ f32x2 col4(const f32x2* qp, float4 kc, float4 w4, f32x2 acc) {
    const f32x2 one = {1.0f, 1.0f};
    f32x2 d0 = __builtin_elementwise_fma(qp[0], (f32x2){kc.x, kc.x}, one);
    f32x2 d1 = __builtin_elementwise_fma(qp[1], (f32x2){kc.y, kc.y}, one);
    f32x2 d2 = __builtin_elementwise_fma(qp[2], (f32x2){kc.z, kc.z}, one);
    f32x2 d3 = __builtin_elementwise_fma(qp[3], (f32x2){kc.w, kc.w}, one);
    f32x2 ab = d0 * d1, cd = d2 * d3;
    f32x2 n1 = __builtin_elementwise_fma((f32x2){w4.y, w4.y}, d0, (f32x2){w4.x, w4.x} * d1);
    f32x2 n2 = __builtin_elementwise_fma((f32x2){w4.w, w4.w}, d2, (f32x2){w4.z, w4.z} * d3);
    f32x2 num = __builtin_elementwise_fma(n2, ab, n1 * cd);
    f32x2 den = ab * cd;
    f32x2 r = {rcp_(den.x), rcp_(den.y)};
    return __builtin_elementwise_fma(num, r, acc);
}

__global__ __launch_bounds__(256, 4) void scores_v3(const float* __restrict__ eqT,
                                                    const float* __restrict__ ek,
                                                    const float* __restrict__ wv,
                                                    float* __restrict__ scpart) {
    __shared__ f32x2 qs[64][32];  // [h][q-pair]
    __shared__ float ks[64][68];  // [k-row][h]
    const int bz = blockIdx.z;    // b*4 + hs
    const int b = bz >> 2, hs = bz & 3;
    const int h0 = hs * 64;
    const int i0 = blockIdx.y * 64, j0 = blockIdx.x * 64;
    const int tid = threadIdx.x;
    const int kq = tid & 15, qq = tid >> 4;  // k cols 4kq+{0..3}; q rows 4qq+{0..3}
#pragma unroll
    for (int t = 0; t < 8; ++t) {  // stage q: 64h x 32 pairs
        int idx = t * 256 + tid;
        int hq = idx >> 5, pr = idx & 31;
        qs[hq][pr] = *(const f32x2*)(eqT + (size_t)(h0 + hq) * TOTR + b * QN + i0 + 2 * pr);
    }
#pragma unroll
    for (int t = 0; t < 4; ++t) {  // stage k: 64 rows x 64h
        int idx = t * 256 + tid;
        int row = idx >> 4, c4 = idx & 15;
        *(float4*)&ks[row][c4 * 4] =
            *(const float4*)(ek + (size_t)(b * KVN + j0 + row) * H_ + h0 + c4 * 4);
    }
    __syncthreads();
    f32x2 acc[2][4] = {};  // [q-pair-half][k]
#pragma unroll
    for (int hh = 0; hh < 64; hh += 4) {
        float4 w4 = *(const float4*)(wv + h0 + hh);  // uniform -> s_load
        f32x2 qp0[4], qp1[4];
#pragma unroll
        for (int e = 0; e < 4; ++e) {
            float4 Q = *(const float4*)&qs[hh + e][2 * qq];
            qp0[e].x = Q.x; qp0[e].y = Q.y;
            qp1[e].x = Q.z; qp1[e].y = Q.w;
        }
#pragma unroll
        for (int r = 0; r < 4; ++r) {
            float4 K = *(const float4*)&ks[4 * kq + r][hh];
            acc[0][r] = col4(qp0, K, w4, acc[0][r]);
            acc[1][r] = col4(qp1, K, w4, acc[1][r]);
        }
    }
    float* base = scpart + (size_t)hs * TOTR * KVN +
                  (size_t)(b * QN + i0 + 4 * qq) * KVN + j0 + 4 * kq;
    float4 o0 = {-2.f * acc[0][0].x, -2.f * acc[0][1].x, -2.f * acc[0][2].x, -2.f * acc[0][3].x};
    float4 o1 = {-2.f * acc[0][0].y, -2.f * acc[0][1].y, -2.f * acc[0][2].y, -2.f * acc[0][3].y};
    float4 o2 = {-2.f * acc[1][0].x, -2.f * acc[1][1].x, -2.f * acc[1][2].x, -2.f * acc[1][3].x};
    float4 o3 = {-2.f * acc[1][0].y, -2.f * acc[1][1].y, -2.f * acc[1][2].y, -2.f * acc[1][3].y};
    *(float4*)(base) = o0;
    *(float4*)(base + KVN) = o1;
    *(float4*)(base + 2 * KVN) = o2;
    *(float4*)(base + 3 * KVN) = o3;
}

// ---------------- softmax v2: sum 4 partials, no max pass (|s| <= 2||wv||_1 ~ 26) -------
__global__ __launch_bounds__(256) void softmax2(const float* __restrict__ scpart,
                                                float* __restrict__ attn,
                                                u16* __restrict__ at_hi,
                                                u16* __restrict__ at_lo) {
    const size_t PS = (size_t)TOTR * KVN;  // partial stride
    int row = blockIdx.x;
    int tid = threadIdx.x;
    const float* p = scpart + (size_t)row * KVN;
    float x0 = 0.f, x1 = 0.f;
#pragma unroll
    for (int hsplit = 0; hsplit < 4; ++hsplit) {
        x0 += p[hsplit * PS + tid];
        x1 += p[hsplit * PS + tid + 256];
    }
    float e0 = __expf(x0), e1 = __expf(x1);
    float s = e0 + e1;
#pragma unroll
    for (int d = 1; d < 64; d <<= 1) s += __shfl_xor(s, d);
    __shared__ float reds[4];
    int wave = tid >> 6, lane = tid & 63;
    if (lane == 0) reds[wave] = s;
    __syncthreads();
    s = reds[0] + reds[1] + reds[2] + reds[3];
    float inv = rcp_(s);
    float r0v = e0 * inv, r1v = e1 * inv;
    float* o = attn + (size_t)row * KVN;
    o[tid] = r0v;
    o[tid + 256] = r1v;
    u16 h, l;
    size_t base = (size_t)row * KVN;
    split2(r0v, h, l);
    at_hi[base + tid] = h; at_lo[base + tid] = l;
    split2(r1v, h, l);
    at_hi[base + tid + 256] = h; at_lo[base + tid + 256] = l;
}

// ---------------- out: out[b][i][n] = sum_j attn[b][i][j] * v[b][j][n] ------------------
__global__ __launch_bounds__(256) void out_mfma(const u16* __restrict__ vt_hi, const u16* __restrict__ vt_lo,
                                                const u16* __restrict__ at_hi, const u16* __restrict__ at_lo,
                                                float* __restrict__ out) {
    const int b = blockIdx.z;
    const u16* __restrict__ Ah_g = vt_hi + (size_t)b * VD_ * KVN;
    const u16* __restrict__ Al_g = vt_lo + (size_t)b * VD_ * KVN;
    const u16* __restrict__ Bh_g = at_hi + (size_t)b * QN * KVN;
    const u16* __restrict__ Bl_g = at_lo + (size_t)b * QN * KVN;
    float* __restrict__ outb = out + (size_t)b * QN * VD_;
    __shared__ u16 Ash[4][32][8], Asl[4][32][8], Bsh[4][32][8], Bsl[4][32][8];
    const int tid = threadIdx.x;
    const int wave = tid >> 6, lane = tid & 63;
    const int fl = lane & 15, kg = lane >> 4;
    const int r0 = blockIdx.y * 32;  // n-tile
    const int c0 = blockIdx.x * 32;  // i-tile
    const int ar = 16 * (wave & 1), bc = 16 * (wave >> 1);
    const int frow = (tid & 127) >> 2, fkq = tid & 3, fsel = tid >> 7;
    f32x4 acc = {};
    for (int k0 = 0; k0 < KVN; k0 += 32) {
        __syncthreads();
        {
            const u16* as = (fsel ? Al_g : Ah_g) + (size_t)(r0 + frow) * KVN + k0 + fkq * 8;
            u16* ad = fsel ? &Asl[fkq][frow][0] : &Ash[fkq][frow][0];
            *(uint4*)ad = *(const uint4*)as;
            const u16* bs = (fsel ? Bl_g : Bh_g) + (size_t)(c0 + frow) * KVN + k0 + fkq * 8;
            u16* bd = fsel ? &Bsl[fkq][frow][0] : &Bsh[fkq][frow][0];
            *(uint4*)bd = *(const uint4*)bs;
        }
        __syncthreads();
        bf16x8 a_h = *(const bf16x8*)&Ash[kg][ar + fl][0];
        bf16x8 a_l = *(const bf16x8*)&Asl[kg][ar + fl][0];
        bf16x8 b_h = *(const bf16x8*)&Bsh[kg][bc + fl][0];
        bf16x8 b_l = *(const bf16x8*)&Bsl[kg][bc + fl][0];
        acc = __builtin_amdgcn_mfma_f32_16x16x32_bf16(a_h, b_h, acc, 0, 0, 0);
        acc = __builtin_amdgcn_mfma_f32_16x16x32_bf16(a_h, b_l, acc, 0, 0, 0);
        acc = __builtin_amdgcn_mfma_f32_16x16x32_bf16(a_l, b_h, acc, 0, 0, 0);
    }
    const int rg = kg * 4;
    float4 o = {acc[0], acc[1], acc[2], acc[3]};
    *(float4*)(outb + (size_t)(c0 + bc + fl) * VD_ + r0 + ar + rg) = o;
}

extern "C" void kernel_launch(void* const* d_in, const int* in_sizes, int n_in,
                              void* d_out, int out_size, void* d_ws, size_t ws_size,
                              hipStream_t stream) {
    const float* q  = (const float*)d_in[0];
    const float* k  = (const float*)d_in[1];
    const float* v  = (const float*)d_in[2];
    const float* Wq = (const float*)d_in[3];
    const float* Wk = (const float*)d_in[4];
    const float* wv = (const float*)d_in[5];
    float* out  = (float*)d_out;                   // [B, QN, VD]
    float* attn = out + (size_t)B_ * QN * VD_;     // [B, QN, KVN]

    float* eqT = (float*)d_ws;                     // [H][2048] f32  (= exp2(qh'), transposed)
    float* ek  = eqT + H_ * TOTR;                  // [2048][H] f32
    u16* q_hi = (u16*)(ek + TOTR * H_);            // [2048][512] u16 each
    u16* q_lo = q_hi + 2048 * 512;
    u16* k_hi = q_lo + 2048 * 512;
    u16* k_lo = k_hi + 2048 * 512;
    u16* w_hi = k_lo + 2048 * 512;                 // [512][512] (Wq rows 0-255, Wk 256-511)
    u16* w_lo = w_hi + 512 * 512;
    u16* vt_hi = w_lo + 512 * 512;                 // [4][256][512]
    u16* vt_lo = vt_hi + (size_t)B_ * VD_ * KVN;
    float* scpart = (float*)(vt_lo + (size_t)B_ * VD_ * KVN);  // [4][2048][512] f32
    u16* at_hi = q_hi;                             // alias: q planes dead after proj
    u16* at_lo = q_lo;

    prep<<<2432, 256, 0, stream>>>(q, k, Wq, Wk, v, q_hi, q_lo, k_hi, k_lo,
                                   w_hi, w_lo, vt_hi, vt_lo);
    proj_mfma<<<dim3(H_ / 32, 2048 / 32, 2), 256, 0, stream>>>(q_hi, q_lo, k_hi, k_lo,
                                                               w_hi, w_lo, eqT, ek);
    scores_v3<<<dim3(KVN / 64, QN / 64, B_ * 4), 256, 0, stream>>>(eqT, ek, wv, scpart);
    softmax2<<<TOTR, 256, 0, stream>>>(scpart, attn, at_hi, at_lo);
    out_mfma<<<dim3(QN / 32, VD_ / 32, B_), 256, 0, stream>>>(vt_hi, vt_lo, at_hi, at_lo, out);
}